// Round 2
// baseline (340.644 us; speedup 1.0000x reference)
//
#include <hip/hip_runtime.h>
#include <math.h>

#define SEQ 4096
#define LOG2SEQ 12
#define TOPK 8
#define NB 16
#define ND 128
#define NEGINF (-3.402823466e+38f)

__device__ __forceinline__ int rev12(int x) {
    return (int)(__brev((unsigned)x) >> (32 - LOG2SEQ));
}

// Batched tiled transpose: in [batch, R, C] -> out [batch, C, R]
__device__ __forceinline__ void transpose_body(const float* __restrict__ inb,
                                               float* __restrict__ outb,
                                               int R, int C) {
    __shared__ float tile[32][33];
    const int c0 = blockIdx.x * 32, r0 = blockIdx.y * 32;
#pragma unroll
    for (int j = 0; j < 32; j += 8) {
        tile[threadIdx.y + j][threadIdx.x] =
            inb[(size_t)(r0 + threadIdx.y + j) * C + (c0 + threadIdx.x)];
    }
    __syncthreads();
#pragma unroll
    for (int j = 0; j < 32; j += 8) {
        outb[(size_t)(c0 + threadIdx.y + j) * R + (r0 + threadIdx.x)] =
            tile[threadIdx.x][threadIdx.y + j];
    }
}

// All three input transposes in one dispatch: z in [0, 3*NB)
__global__ __launch_bounds__(256) void transpose3_k(const float* __restrict__ Q,
                                                    const float* __restrict__ K,
                                                    const float* __restrict__ V,
                                                    float* __restrict__ Qt,
                                                    float* __restrict__ Kt,
                                                    float* __restrict__ Vt) {
    const int which = blockIdx.z / NB;
    const int b = blockIdx.z % NB;
    const size_t bo = (size_t)b * SEQ * ND;
    const float* in = (which == 0) ? Q : (which == 1) ? K : V;
    float* out = (which == 0) ? Qt : (which == 1) ? Kt : Vt;
    transpose_body(in + bo, out + bo, SEQ, ND);  // [S,D] -> [D,S]
}

__global__ __launch_bounds__(256) void transpose_back_k(const float* __restrict__ in,
                                                        float* __restrict__ out) {
    const size_t bo = (size_t)blockIdx.z * SEQ * ND;
    transpose_body(in + bo, out + bo, ND, SEQ);  // [D,S] -> [S,D]
}

// One workgroup per (b,d) lane: FFT cross-correlation -> top-8 -> time-delay agg.
// Qt/Kt/Vt are [B*D, SEQ]. Ot may alias Qt (each WG reads its Qt row before
// writing the same addresses as its Ot row).
__global__ __launch_bounds__(256) void corr_topk_agg_k(const float* Qt,
                                                       const float* __restrict__ Kt,
                                                       const float* __restrict__ Vt,
                                                       float* Ot) {
    __shared__ __align__(16) float re[SEQ];
    __shared__ __align__(16) float im[SEQ];
    __shared__ float twc[SEQ / 2];
    __shared__ float tws[SEQ / 2];
    __shared__ float sval[4];
    __shared__ int sidx[4];
    __shared__ float wsel[TOPK];
    __shared__ int dsel[TOPK];

    const int tid = threadIdx.x;
    const size_t row = (size_t)blockIdx.x * SEQ;

    // Twiddle table: tw[j] = exp(-2*pi*i*j/SEQ), j in [0, SEQ/2). Precise sincos.
    for (int j = tid; j < SEQ / 2; j += 256) {
        float s, c;
        sincosf(-6.283185307179586f * (float)j / (float)SEQ, &s, &c);
        twc[j] = c;
        tws[j] = s;
    }

    // Load z = Q + i*K (coalesced float4).
    {
        const float4* Q4 = (const float4*)(Qt + row);
        const float4* K4 = (const float4*)(Kt + row);
        for (int t = tid; t < SEQ / 4; t += 256) {
            ((float4*)re)[t] = Q4[t];
            ((float4*)im)[t] = K4[t];
        }
    }
    __syncthreads();

    // Forward FFT: fused double radix-2 (radix-4 dataflow), DIF, exp(-),
    // natural input -> bit-reversed output. Identical stage math/order to the
    // plain radix-2 version, so rev12-based spectrum indexing is unchanged.
    for (int h = 2048; h >= 2; h >>= 2) {
        const int hh = h >> 1;
        const int sA = SEQ / (2 * h);  // stage-A twiddle stride; stage-B = 2*sA
        for (int g = tid; g < SEQ / 4; g += 256) {
            const int pos = g & (hh - 1);
            const int i0 = ((g - pos) << 2) + pos;
            const int i1 = i0 + hh, i2 = i0 + h, i3 = i2 + hh;
            const float e0r = re[i0], e0i = im[i0];
            const float e1r = re[i1], e1i = im[i1];
            const float e2r = re[i2], e2i = im[i2];
            const float e3r = re[i3], e3i = im[i3];
            const int ta = pos * sA;
            const float c1 = twc[ta], s1 = tws[ta];
            const float cB = twc[2 * ta], sB = tws[2 * ta];
            // stage A (half = h): pairs (e0,e2) tw W^ta, (e1,e3) tw W^ta * (-i)
            const float f0r = e0r + e2r, f0i = e0i + e2i;
            float dr = e0r - e2r, di = e0i - e2i;
            const float f2r = dr * c1 - di * s1, f2i = dr * s1 + di * c1;
            const float f1r = e1r + e3r, f1i = e1i + e3i;
            dr = e1r - e3r;
            di = e1i - e3i;
            // (dr + i*di) * (s1 - i*c1):
            const float f3r = dr * s1 + di * c1;
            const float f3i = di * s1 - dr * c1;
            // stage B (half = hh): both pairs tw W^(2*ta)
            re[i0] = f0r + f1r;
            im[i0] = f0i + f1i;
            dr = f0r - f1r;
            di = f0i - f1i;
            re[i1] = dr * cB - di * sB;
            im[i1] = dr * sB + di * cB;
            re[i2] = f2r + f3r;
            im[i2] = f2i + f3i;
            dr = f2r - f3r;
            di = f2i - f3i;
            re[i3] = dr * cB - di * sB;
            im[i3] = dr * sB + di * cB;
        }
        __syncthreads();
    }

    // Cross spectrum P[f] = Qhat[f] * conj(Khat[f]) / SEQ, done in the
    // bit-reversed domain (register-staged; one read barrier, one write barrier).
    float ar_[9], ai_[9], br_[9], bi_[9];
#pragma unroll
    for (int q = 0; q < 9; ++q) {
        const int f = tid + (q << 8);
        if (f <= SEQ / 2) {
            const int pa = rev12(f);
            const int pb = rev12((SEQ - f) & (SEQ - 1));
            ar_[q] = re[pa];
            ai_[q] = im[pa];
            br_[q] = re[pb];
            bi_[q] = im[pb];
        }
    }
    __syncthreads();
#pragma unroll
    for (int q = 0; q < 9; ++q) {
        const int f = tid + (q << 8);
        if (f <= SEQ / 2) {
            const float ar = ar_[q], ai = ai_[q], br = br_[q], bi = bi_[q];
            const float Qr = 0.5f * (ar + br), Qi = 0.5f * (ai - bi);
            const float Kr = 0.5f * (ai + bi), Ki = 0.5f * (br - ar);
            const float invS = 1.0f / (float)SEQ;
            const float Pr = (Qr * Kr + Qi * Ki) * invS;
            const float Pi = (Qi * Kr - Qr * Ki) * invS;
            const int pa = rev12(f);
            const int pb = rev12((SEQ - f) & (SEQ - 1));
            re[pa] = Pr;
            im[pa] = Pi;
            re[pb] = Pr;
            im[pb] = -Pi;
        }
    }
    __syncthreads();

    // Inverse FFT: fused double radix-2 DIT, exp(+), bit-reversed -> natural.
    // (1/SEQ already folded into P.)
    for (int hh = 1; hh <= 1024; hh <<= 2) {
        const int sA = SEQ / (2 * hh);  // stage-A twiddle stride
        const int sB = SEQ / (4 * hh);  // stage-B twiddle stride
        for (int g = tid; g < SEQ / 4; g += 256) {
            const int pos = g & (hh - 1);
            const int i0 = ((g - pos) << 2) + pos;
            const int i1 = i0 + hh, i2 = i0 + 2 * hh, i3 = i0 + 3 * hh;
            const float e0r = re[i0], e0i = im[i0];
            const float e1r = re[i1], e1i = im[i1];
            const float e2r = re[i2], e2i = im[i2];
            const float e3r = re[i3], e3i = im[i3];
            const int ta = pos * sA;
            const float cA = twc[ta], sAv = -tws[ta];
            const int tb = pos * sB;
            const float cB = twc[tb], sBv = -tws[tb];
            // stage A (half = hh): both pairs tw conj(W^ta)
            float tr = e1r * cA - e1i * sAv, ti = e1r * sAv + e1i * cA;
            const float f0r = e0r + tr, f0i = e0i + ti;
            const float f1r = e0r - tr, f1i = e0i - ti;
            tr = e3r * cA - e3i * sAv;
            ti = e3r * sAv + e3i * cA;
            const float f2r = e2r + tr, f2i = e2i + ti;
            const float f3r = e2r - tr, f3i = e2i - ti;
            // stage B (half = 2*hh): pair (f0,f2) tw conj(W^tb);
            // pair (f1,f3) tw conj(W^(tb + SEQ/4)) = conj(W^tb) * i = (-sBv, cB)
            tr = f2r * cB - f2i * sBv;
            ti = f2r * sBv + f2i * cB;
            re[i0] = f0r + tr;
            im[i0] = f0i + ti;
            re[i2] = f0r - tr;
            im[i2] = f0i - ti;
            tr = -f3r * sBv - f3i * cB;
            ti = f3r * cB - f3i * sBv;
            re[i1] = f1r + tr;
            im[i1] = f1i + ti;
            re[i3] = f1r - tr;
            im[i3] = f1i - ti;
        }
        __syncthreads();
    }
    // re[t] now holds corr[t] (imaginary residue discarded).

    // Stage V row into im[] (free after inverse FFT). Visibility to the
    // aggregation phase is guaranteed by the top-k barriers below.
    {
        const float4* V4 = (const float4*)(Vt + row);
        for (int t = tid; t < SEQ / 4; t += 256) {
            ((float4*)im)[t] = V4[t];
        }
    }

    // Top-8 selection (argmax x8, wave-shuffle reduce; ties -> lower index,
    // matching jax.lax.top_k).
    for (int it = 0; it < TOPK; ++it) {
        float best = NEGINF;
        int bidx = 0;
#pragma unroll
        for (int j = 0; j < SEQ / 256; ++j) {
            const int t = tid + (j << 8);
            const float v = re[t];
            if (v > best) {  // strict: keeps lowest index on ties (t ascending)
                best = v;
                bidx = t;
            }
        }
#pragma unroll
        for (int off = 32; off > 0; off >>= 1) {
            const float ov = __shfl_down(best, off);
            const int oi = __shfl_down(bidx, off);
            if (ov > best || (ov == best && oi < bidx)) {
                best = ov;
                bidx = oi;
            }
        }
        if ((tid & 63) == 0) {
            sval[tid >> 6] = best;
            sidx[tid >> 6] = bidx;
        }
        __syncthreads();
        if (tid == 0) {
            float bv = sval[0];
            int bi2 = sidx[0];
#pragma unroll
            for (int w = 1; w < 4; ++w) {
                const float ov = sval[w];
                const int oi = sidx[w];
                if (ov > bv || (ov == bv && oi < bi2)) {
                    bv = ov;
                    bi2 = oi;
                }
            }
            wsel[it] = bv;
            dsel[it] = bi2;
            re[bi2] = NEGINF;  // exclude from subsequent iterations
        }
        __syncthreads();
    }

    // Aggregation: out[t] = sum_k w_k * V[(t + delay_k) & (SEQ-1)].
    float w[TOPK];
    int dl[TOPK];
#pragma unroll
    for (int k = 0; k < TOPK; ++k) {
        w[k] = wsel[k];
        dl[k] = dsel[k];
    }
    for (int j = 0; j < SEQ / 256; ++j) {
        const int t = tid + (j << 8);
        float acc = 0.0f;
#pragma unroll
        for (int k = 0; k < TOPK; ++k) {
            acc += w[k] * im[(t + dl[k]) & (SEQ - 1)];
        }
        Ot[row + t] = acc;
    }
}

extern "C" void kernel_launch(void* const* d_in, const int* in_sizes, int n_in,
                              void* d_out, int out_size, void* d_ws, size_t ws_size,
                              hipStream_t stream) {
    const float* Q = (const float*)d_in[0];
    const float* K = (const float*)d_in[1];
    const float* V = (const float*)d_in[2];
    float* out = (float*)d_out;

    const size_t n = (size_t)NB * ND * SEQ;  // 8388608 elements per tensor
    float* Qt = (float*)d_ws;  // [B*D, S]; also reused as Ot (safe aliasing)
    float* Kt = Qt + n;
    float* Vt = Kt + n;

    dim3 tb(32, 8, 1);

    // [B,S,D] -> [B,D,S] for Q, K, V in one dispatch.
    dim3 g1(ND / 32, SEQ / 32, 3 * NB);
    hipLaunchKernelGGL(transpose3_k, g1, tb, 0, stream, Q, K, V, Qt, Kt, Vt);

    // Per-lane FFT correlation + top-k + aggregation. Ot aliases Qt.
    hipLaunchKernelGGL(corr_topk_agg_k, dim3(NB * ND), dim3(256), 0, stream,
                       Qt, Kt, Vt, Qt);

    // [B,D,S] -> [B,S,D]
    dim3 g3(SEQ / 32, ND / 32, NB);
    hipLaunchKernelGGL(transpose_back_k, g3, tb, 0, stream, Qt, out);
}

// Round 3
// 259.013 us; speedup vs baseline: 1.3152x; 1.3152x over previous
//
#include <hip/hip_runtime.h>
#include <math.h>

#define SEQ 4096
#define LOG2SEQ 12
#define TOPK 8
#define NB 16
#define ND 128
#define NEGINF (-3.402823466e+38f)

// LDS anti-bank-conflict padding: insert one float per 32.
#define PADF(i) ((i) + ((i) >> 5))

__device__ __forceinline__ int rev12(int x) {
    return (int)(__brev((unsigned)x) >> (32 - LOG2SEQ));
}

// Batched tiled transpose: in [batch, R, C] -> out [batch, C, R]
__device__ __forceinline__ void transpose_body(const float* __restrict__ inb,
                                               float* __restrict__ outb,
                                               int R, int C) {
    __shared__ float tile[32][33];
    const int c0 = blockIdx.x * 32, r0 = blockIdx.y * 32;
#pragma unroll
    for (int j = 0; j < 32; j += 8) {
        tile[threadIdx.y + j][threadIdx.x] =
            inb[(size_t)(r0 + threadIdx.y + j) * C + (c0 + threadIdx.x)];
    }
    __syncthreads();
#pragma unroll
    for (int j = 0; j < 32; j += 8) {
        outb[(size_t)(c0 + threadIdx.y + j) * R + (r0 + threadIdx.x)] =
            tile[threadIdx.x][threadIdx.y + j];
    }
}

// All three input transposes in one dispatch: z in [0, 3*NB)
__global__ __launch_bounds__(256) void transpose3_k(const float* __restrict__ Q,
                                                    const float* __restrict__ K,
                                                    const float* __restrict__ V,
                                                    float* __restrict__ Qt,
                                                    float* __restrict__ Kt,
                                                    float* __restrict__ Vt) {
    const int which = blockIdx.z / NB;
    const int b = blockIdx.z % NB;
    const size_t bo = (size_t)b * SEQ * ND;
    const float* in = (which == 0) ? Q : (which == 1) ? K : V;
    float* out = (which == 0) ? Qt : (which == 1) ? Kt : Vt;
    transpose_body(in + bo, out + bo, SEQ, ND);  // [S,D] -> [D,S]
}

__global__ __launch_bounds__(256) void transpose_back_k(const float* __restrict__ in,
                                                        float* __restrict__ out) {
    const size_t bo = (size_t)blockIdx.z * SEQ * ND;
    transpose_body(in + bo, out + bo, ND, SEQ);  // [D,S] -> [S,D]
}

// One workgroup per (b,d) lane: FFT cross-correlation -> top-8 -> time-delay agg.
// Qt/Kt/Vt are [B*D, SEQ]. Ot may alias Qt (each WG reads its Qt row before
// writing the same addresses as its Ot row).
__global__ __launch_bounds__(256) void corr_topk_agg_k(const float* Qt,
                                                       const float* __restrict__ Kt,
                                                       const float* __restrict__ Vt,
                                                       float* Ot) {
    __shared__ float re[SEQ + SEQ / 32];
    __shared__ float im[SEQ + SEQ / 32];
    __shared__ float twc[SEQ / 2 + SEQ / 64];
    __shared__ float tws[SEQ / 2 + SEQ / 64];
    __shared__ float sval[4];
    __shared__ int sidx[4];
    __shared__ float wsel[TOPK];
    __shared__ int dsel[TOPK];

    const int tid = threadIdx.x;
    const size_t row = (size_t)blockIdx.x * SEQ;

    // Twiddle table: tw[j] = exp(-2*pi*i*j/SEQ), j in [0, SEQ/2). Precise sincos.
    for (int j = tid; j < SEQ / 2; j += 256) {
        float s, c;
        sincosf(-6.283185307179586f * (float)j / (float)SEQ, &s, &c);
        twc[PADF(j)] = c;
        tws[PADF(j)] = s;
    }

    // Load z = Q + i*K (coalesced float4 from global; scalar LDS writes since
    // padding breaks 16B contiguity at 32-float boundaries).
    {
        const float4* Q4 = (const float4*)(Qt + row);
        const float4* K4 = (const float4*)(Kt + row);
        for (int t = tid; t < SEQ / 4; t += 256) {
            const float4 q = Q4[t];
            const float4 k = K4[t];
            const int b0 = PADF(4 * t);  // 4t..4t+3 never cross a pad boundary
            re[b0] = q.x; re[b0 + 1] = q.y; re[b0 + 2] = q.z; re[b0 + 3] = q.w;
            im[b0] = k.x; im[b0 + 1] = k.y; im[b0 + 2] = k.z; im[b0 + 3] = k.w;
        }
    }
    __syncthreads();

    // Forward FFT: fused double radix-2 (radix-4 dataflow), DIF, exp(-),
    // natural input -> bit-reversed output.
    for (int h = 2048; h >= 2; h >>= 2) {
        const int hh = h >> 1;
        const int sA = SEQ / (2 * h);  // stage-A twiddle stride; stage-B = 2*sA
        for (int g = tid; g < SEQ / 4; g += 256) {
            const int pos = g & (hh - 1);
            const int i0 = ((g - pos) << 2) + pos;
            const int p0 = PADF(i0), p1 = PADF(i0 + hh);
            const int p2 = PADF(i0 + h), p3 = PADF(i0 + h + hh);
            const float e0r = re[p0], e0i = im[p0];
            const float e1r = re[p1], e1i = im[p1];
            const float e2r = re[p2], e2i = im[p2];
            const float e3r = re[p3], e3i = im[p3];
            const int ta = pos * sA;
            const int pta = PADF(ta), ptb = PADF(2 * ta);
            const float c1 = twc[pta], s1 = tws[pta];
            const float cB = twc[ptb], sB = tws[ptb];
            // stage A (half = h): pairs (e0,e2) tw W^ta, (e1,e3) tw W^ta * (-i)
            const float f0r = e0r + e2r, f0i = e0i + e2i;
            float dr = e0r - e2r, di = e0i - e2i;
            const float f2r = dr * c1 - di * s1, f2i = dr * s1 + di * c1;
            const float f1r = e1r + e3r, f1i = e1i + e3i;
            dr = e1r - e3r;
            di = e1i - e3i;
            // (dr + i*di) * (s1 - i*c1):
            const float f3r = dr * s1 + di * c1;
            const float f3i = di * s1 - dr * c1;
            // stage B (half = hh): both pairs tw W^(2*ta)
            re[p0] = f0r + f1r;
            im[p0] = f0i + f1i;
            dr = f0r - f1r;
            di = f0i - f1i;
            re[p1] = dr * cB - di * sB;
            im[p1] = dr * sB + di * cB;
            re[p2] = f2r + f3r;
            im[p2] = f2i + f3i;
            dr = f2r - f3r;
            di = f2i - f3i;
            re[p3] = dr * cB - di * sB;
            im[p3] = dr * sB + di * cB;
        }
        __syncthreads();
    }

    // Cross spectrum P[f] = Qhat[f] * conj(Khat[f]) / SEQ, done in the
    // bit-reversed domain (register-staged; one read barrier, one write barrier).
    float ar_[9], ai_[9], br_[9], bi_[9];
#pragma unroll
    for (int q = 0; q < 9; ++q) {
        const int f = tid + (q << 8);
        if (f <= SEQ / 2) {
            const int pa = PADF(rev12(f));
            const int pb = PADF(rev12((SEQ - f) & (SEQ - 1)));
            ar_[q] = re[pa];
            ai_[q] = im[pa];
            br_[q] = re[pb];
            bi_[q] = im[pb];
        }
    }
    __syncthreads();
#pragma unroll
    for (int q = 0; q < 9; ++q) {
        const int f = tid + (q << 8);
        if (f <= SEQ / 2) {
            const float ar = ar_[q], ai = ai_[q], br = br_[q], bi = bi_[q];
            const float Qr = 0.5f * (ar + br), Qi = 0.5f * (ai - bi);
            const float Kr = 0.5f * (ai + bi), Ki = 0.5f * (br - ar);
            const float invS = 1.0f / (float)SEQ;
            const float Pr = (Qr * Kr + Qi * Ki) * invS;
            const float Pi = (Qi * Kr - Qr * Ki) * invS;
            const int pa = PADF(rev12(f));
            const int pb = PADF(rev12((SEQ - f) & (SEQ - 1)));
            re[pa] = Pr;
            im[pa] = Pi;
            re[pb] = Pr;
            im[pb] = -Pi;
        }
    }
    __syncthreads();

    // Inverse FFT: fused double radix-2 DIT, exp(+), bit-reversed -> natural.
    // (1/SEQ already folded into P.)
    for (int hh = 1; hh <= 1024; hh <<= 2) {
        const int sA = SEQ / (2 * hh);  // stage-A twiddle stride
        const int sB = SEQ / (4 * hh);  // stage-B twiddle stride
        for (int g = tid; g < SEQ / 4; g += 256) {
            const int pos = g & (hh - 1);
            const int i0 = ((g - pos) << 2) + pos;
            const int p0 = PADF(i0), p1 = PADF(i0 + hh);
            const int p2 = PADF(i0 + 2 * hh), p3 = PADF(i0 + 3 * hh);
            const float e0r = re[p0], e0i = im[p0];
            const float e1r = re[p1], e1i = im[p1];
            const float e2r = re[p2], e2i = im[p2];
            const float e3r = re[p3], e3i = im[p3];
            const int pta = PADF(pos * sA), ptb = PADF(pos * sB);
            const float cA = twc[pta], sAv = -tws[pta];
            const float cB = twc[ptb], sBv = -tws[ptb];
            // stage A (half = hh): both pairs tw conj(W^ta)
            float tr = e1r * cA - e1i * sAv, ti = e1r * sAv + e1i * cA;
            const float f0r = e0r + tr, f0i = e0i + ti;
            const float f1r = e0r - tr, f1i = e0i - ti;
            tr = e3r * cA - e3i * sAv;
            ti = e3r * sAv + e3i * cA;
            const float f2r = e2r + tr, f2i = e2i + ti;
            const float f3r = e2r - tr, f3i = e2i - ti;
            // stage B (half = 2*hh): pair (f0,f2) tw conj(W^tb);
            // pair (f1,f3) tw conj(W^(tb + SEQ/4)) = conj(W^tb) * i = (-sBv, cB)
            tr = f2r * cB - f2i * sBv;
            ti = f2r * sBv + f2i * cB;
            re[p0] = f0r + tr;
            im[p0] = f0i + ti;
            re[p2] = f0r - tr;
            im[p2] = f0i - ti;
            tr = -f3r * sBv - f3i * cB;
            ti = f3r * cB - f3i * sBv;
            re[p1] = f1r + tr;
            im[p1] = f1i + ti;
            re[p3] = f1r - tr;
            im[p3] = f1i - ti;
        }
        __syncthreads();
    }
    // re[t] now holds corr[t] (imaginary residue discarded).

    // Stage V row into im[] (free after inverse FFT). Visibility to the
    // aggregation phase is guaranteed by the top-k barriers below.
    {
        const float4* V4 = (const float4*)(Vt + row);
        for (int t = tid; t < SEQ / 4; t += 256) {
            const float4 v = V4[t];
            const int b0 = PADF(4 * t);
            im[b0] = v.x; im[b0 + 1] = v.y; im[b0 + 2] = v.z; im[b0 + 3] = v.w;
        }
    }

    // Top-8 selection (argmax x8, wave-shuffle reduce; ties -> lower index,
    // matching jax.lax.top_k).
    for (int it = 0; it < TOPK; ++it) {
        float best = NEGINF;
        int bidx = 0;
#pragma unroll
        for (int j = 0; j < SEQ / 256; ++j) {
            const int t = tid + (j << 8);
            const float v = re[PADF(t)];
            if (v > best) {  // strict: keeps lowest index on ties (t ascending)
                best = v;
                bidx = t;
            }
        }
#pragma unroll
        for (int off = 32; off > 0; off >>= 1) {
            const float ov = __shfl_down(best, off);
            const int oi = __shfl_down(bidx, off);
            if (ov > best || (ov == best && oi < bidx)) {
                best = ov;
                bidx = oi;
            }
        }
        if ((tid & 63) == 0) {
            sval[tid >> 6] = best;
            sidx[tid >> 6] = bidx;
        }
        __syncthreads();
        if (tid == 0) {
            float bv = sval[0];
            int bi2 = sidx[0];
#pragma unroll
            for (int w = 1; w < 4; ++w) {
                const float ov = sval[w];
                const int oi = sidx[w];
                if (ov > bv || (ov == bv && oi < bi2)) {
                    bv = ov;
                    bi2 = oi;
                }
            }
            wsel[it] = bv;
            dsel[it] = bi2;
            re[PADF(bi2)] = NEGINF;  // exclude from subsequent iterations
        }
        __syncthreads();
    }

    // Aggregation: out[t] = sum_k w_k * V[(t + delay_k) & (SEQ-1)].
    float w[TOPK];
    int dl[TOPK];
#pragma unroll
    for (int k = 0; k < TOPK; ++k) {
        w[k] = wsel[k];
        dl[k] = dsel[k];
    }
    for (int j = 0; j < SEQ / 256; ++j) {
        const int t = tid + (j << 8);
        float acc = 0.0f;
#pragma unroll
        for (int k = 0; k < TOPK; ++k) {
            acc += w[k] * im[PADF((t + dl[k]) & (SEQ - 1))];
        }
        Ot[row + t] = acc;
    }
}

extern "C" void kernel_launch(void* const* d_in, const int* in_sizes, int n_in,
                              void* d_out, int out_size, void* d_ws, size_t ws_size,
                              hipStream_t stream) {
    const float* Q = (const float*)d_in[0];
    const float* K = (const float*)d_in[1];
    const float* V = (const float*)d_in[2];
    float* out = (float*)d_out;

    const size_t n = (size_t)NB * ND * SEQ;  // 8388608 elements per tensor
    float* Qt = (float*)d_ws;  // [B*D, S]; also reused as Ot (safe aliasing)
    float* Kt = Qt + n;
    float* Vt = Kt + n;

    dim3 tb(32, 8, 1);

    // [B,S,D] -> [B,D,S] for Q, K, V in one dispatch.
    dim3 g1(ND / 32, SEQ / 32, 3 * NB);
    hipLaunchKernelGGL(transpose3_k, g1, tb, 0, stream, Q, K, V, Qt, Kt, Vt);

    // Per-lane FFT correlation + top-k + aggregation. Ot aliases Qt.
    hipLaunchKernelGGL(corr_topk_agg_k, dim3(NB * ND), dim3(256), 0, stream,
                       Qt, Kt, Vt, Qt);

    // [B,D,S] -> [B,S,D]
    dim3 g3(SEQ / 32, ND / 32, NB);
    hipLaunchKernelGGL(transpose_back_k, g3, tb, 0, stream, Qt, out);
}